// Round 22
// baseline (754.856 us; speedup 1.0000x reference)
//
#include <hip/hip_runtime.h>
#include <hip/hip_bf16.h>

#define NN 50000
#define NE 100000
#define D 40
#define DE 10
#define DH 128
#define DD 1600   // D*D
#define NEG 6250  // NE/16 edge-groups

typedef __bf16 bf16;
typedef bf16 bf16x8 __attribute__((ext_vector_type(8)));
typedef float f32x4 __attribute__((ext_vector_type(4)));

// Fragment-major layouts (one 16-B chunk per lane, contiguous per wave-load):
//   rF  idx = ((eg*4 + s)*64 + lane)*8 + j  holds r[e=eg*16+(lane&15)][k=(lane>>4)*8+s*32+j]
//   BtF idx = ((nt*4 + s)*64 + lane)*8 + j  holds e2_w[k][d*40+o], j'=nt*16+(lane&15), o=j'/40, d=j'%40

__global__ __launch_bounds__(256) void k_zero(float* __restrict__ p, int n) {
    int t = blockIdx.x * 256 + threadIdx.x;
    if (t < n) p[t] = 0.f;
}

// r (fragment-major) = relu(e_feat @ e1_w + e1_b)
__global__ __launch_bounds__(256) void k_edge1(const float* __restrict__ ef,
                                               const float* __restrict__ w,
                                               const float* __restrict__ b,
                                               bf16* __restrict__ rF) {
    int t = blockIdx.x * 256 + threadIdx.x;  // NE*16 threads exact
    int lane = t & 63;
    int e = (t >> 8) * 16 + (lane & 15);
    int kbase = (lane >> 4) * 8 + ((t >> 6) & 3) * 32;
    float efr[DE];
#pragma unroll
    for (int d = 0; d < DE; ++d) efr[d] = ef[e * DE + d];
    bf16x8 ov;
#pragma unroll
    for (int j = 0; j < 8; ++j) {
        int h = kbase + j;
        float acc = b[h];
#pragma unroll
        for (int d = 0; d < DE; ++d) acc += efr[d] * w[d * DH + h];
        ov[j] = (bf16)fmaxf(acc, 0.f);
    }
    *(bf16x8*)(rF + (size_t)t * 8) = ov;
}

// BtF fragment-major from e2_w (one-time, tiny)
__global__ __launch_bounds__(256) void k_cvtB(const float* __restrict__ w,
                                              bf16* __restrict__ btf) {
    int t = blockIdx.x * 256 + threadIdx.x;  // 100*4*64 = 25600 threads exact
    int lane = t & 63;
    int jp = (t >> 8) * 16 + (lane & 15);
    int kbase = (lane >> 4) * 8 + ((t >> 6) & 3) * 32;
    int o = jp / D, d = jp % D;
    bf16x8 ov;
#pragma unroll
    for (int j = 0; j < 8; ++j) ov[j] = (bf16)w[(kbase + j) * DD + d * D + o];
    *(bf16x8*)(btf + (size_t)t * 8) = ov;
}

// biasP[j'] = e2_b[d*40+o]
__global__ __launch_bounds__(256) void k_cvtBias(const float* __restrict__ b,
                                                 float* __restrict__ bp) {
    int t = blockIdx.x * 256 + threadIdx.x;
    if (t >= DD) return;
    int o = t / D, d = t % D;
    bp[t] = b[d * D + o];
}

// out0 = relu(n_feat @ lin0_w + lin0_b)
__global__ __launch_bounds__(256) void k_lin0(const float* __restrict__ nf,
                                              const float* __restrict__ w,
                                              const float* __restrict__ b,
                                              float* __restrict__ out) {
    int t = blockIdx.x * 256 + threadIdx.x;
    if (t >= NN * D) return;
    int o = t % D, n = t / D;
    float acc = b[o];
    const float* x = nf + n * D;
#pragma unroll
    for (int d = 0; d < D; ++d) acc += x[d] * w[d * D + o];
    out[t] = fmaxf(acc, 0.f);
}

// Fused message step v9: 4 edge-groups per WAVE (16 MFMA per af load -> af L2
// traffic halved vs v7/v8), x rows staged in LDS (frees the 80 VGPRs that made
// G=4 spill in R13; padded [16][11] f32x4 -> <=2-way conflicts, free).
// Block = 4 waves sharing 4 groups; waves 4-way split the m-range (disjoint o
// columns of mb -> every slot written once, no zero-init, no race). Rotated
// m-order decorrelates L2. No prefetch (R21: neutral). Coalesced flush.
__global__ __launch_bounds__(256, 2) void k_msgF9(const float* __restrict__ x,
                                                  const bf16* __restrict__ btf,
                                                  const float* __restrict__ biasp,
                                                  const bf16* __restrict__ rF,
                                                  const int* __restrict__ src,
                                                  const int* __restrict__ dst,
                                                  float* __restrict__ agg) {
    __shared__ f32x4 xs[4][16][11];  // 11.3 KB (pad 10->11: bank spread)
    __shared__ float mb[4][16][41];  // 10.5 KB
    __shared__ int ss_s[64], dd_s[64];
    int tid = threadIdx.x, wave = tid >> 6, lane = tid & 63;
    int r15 = lane & 15, kg = lane >> 4;
    int g0 = blockIdx.x * 4;
    int e0 = g0 * 16;

    if (tid < 64) {
        int e = e0 + tid;
        bool ok = e < NE;
        ss_s[tid] = ok ? src[e] : 0;
        dd_s[tid] = ok ? dst[e] : 0;
    }
    __syncthreads();
    // stage x rows: 64 edges x 10 f32x4 (gathered once per block)
    for (int c = tid; c < 640; c += 256) {
        int el = c / 10, q = c % 10;
        xs[el >> 4][el & 15][q] = *(const f32x4*)(x + (size_t)ss_s[el] * D + q * 4);
    }
    // b fragments for the 4 shared groups (each wave loads all 4)
    bf16x8 b[4][4];
#pragma unroll
    for (int g = 0; g < 4; ++g) {
        int eg = g0 + g;
        if (eg >= NEG) eg = NEG - 1;  // tail clamp (flush guards validity)
#pragma unroll
        for (int s = 0; s < 4; ++s)
            b[g][s] = *(const bf16x8*)(rF + (size_t)((eg * 4 + s) * 64 + lane) * 8);
    }
    __syncthreads();

    int rot = blockIdx.x % 5;
    for (int j = 0; j < 5; ++j) {
        int jr = j + rot;
        if (jr >= 5) jr -= 5;
        int m = wave * 5 + jr;  // waves own disjoint m (o) ranges
        float pe[4] = {0.f, 0.f, 0.f, 0.f}, po[4] = {0.f, 0.f, 0.f, 0.f};
#pragma unroll
        for (int i = 0; i < 5; ++i) {
            int nt = m * 5 + i;
            bf16x8 af[4];
#pragma unroll
            for (int s = 0; s < 4; ++s)
                af[s] = *(const bf16x8*)(btf + (size_t)((nt * 4 + s) * 64 + lane) * 8);
            f32x4 bias = *(const f32x4*)(biasp + nt * 16 + kg * 4);
            int xqi = (4 * i + kg) % 10;  // d0/4, static per (i,kg)
#pragma unroll
            for (int g = 0; g < 4; ++g) {
                f32x4 a = {0.f, 0.f, 0.f, 0.f};
#pragma unroll
                for (int s = 0; s < 4; ++s)
                    a = __builtin_amdgcn_mfma_f32_16x16x32_bf16(af[s], b[g][s], a, 0, 0, 0);
                f32x4 xv = xs[g][r15][xqi];
                float p = (a[0] + bias[0]) * xv[0] + (a[1] + bias[1]) * xv[1] +
                          (a[2] + bias[2]) * xv[2] + (a[3] + bias[3]) * xv[3];
                if (i <= 1) pe[g] += p;            // 16i+4kg < 40 always
                else if (i >= 3) po[g] += p;       // >= 40 always
                else {                              // i==2: kg>=2 -> hi
                    bool hi = kg >= 2;
                    pe[g] += hi ? 0.f : p;
                    po[g] += hi ? p : 0.f;
                }
            }
        }
#pragma unroll
        for (int g = 0; g < 4; ++g) {
            pe[g] += __shfl_xor(pe[g], 16, 64); pe[g] += __shfl_xor(pe[g], 32, 64);
            po[g] += __shfl_xor(po[g], 16, 64); po[g] += __shfl_xor(po[g], 32, 64);
        }
        if (lane < 16) {  // plain stores: unique (g, r15, o) per lane per m
#pragma unroll
            for (int g = 0; g < 4; ++g) {
                mb[g][r15][2 * m] = pe[g];
                mb[g][r15][2 * m + 1] = po[g];
            }
        }
    }
    __syncthreads();
    // coalesced flush: consecutive tid -> consecutive o of same edge row
    for (int idx = tid; idx < 4 * 16 * D; idx += 256) {
        int gl = idx / (16 * D), rem = idx % (16 * D);
        int e_l = rem / D, o = rem % D;
        if (g0 + gl < NEG)
            atomicAdd(&agg[(size_t)dd_s[gl * 16 + e_l] * D + o], mb[gl][e_l][o]);
    }
}

// node update: m = relu(agg + out@res_w + conv_b); out' = [m,out]@msg_w + msg_b
// (+ n_feat if LAST). Non-LAST also re-zeroes agg for the next step.
template <int LAST>
__global__ __launch_bounds__(256) void k_node(const float* __restrict__ out,
                                              float* __restrict__ agg,
                                              const float* __restrict__ res_w,
                                              const float* __restrict__ conv_b,
                                              const float* __restrict__ msg_w,
                                              const float* __restrict__ msg_b,
                                              const float* __restrict__ nf,
                                              float* __restrict__ out_new) {
    __shared__ float xs[6][D], ms[6][D];
    int ni = threadIdx.x / D, o = threadIdx.x % D;
    int n = blockIdx.x * 6 + ni;
    bool ok = (ni < 6) && (n < NN);
    if (ok) xs[ni][o] = out[n * D + o];
    __syncthreads();
    if (ok) {
        float t = conv_b[o] + agg[n * D + o];
        if (!LAST) agg[n * D + o] = 0.f;  // re-zero for next step's atomics
#pragma unroll
        for (int d = 0; d < D; ++d) t += xs[ni][d] * res_w[d * D + o];
        ms[ni][o] = fmaxf(t, 0.f);
    }
    __syncthreads();
    if (ok) {
        float acc = msg_b[o];
#pragma unroll
        for (int d = 0; d < D; ++d)
            acc += ms[ni][d] * msg_w[d * D + o] + xs[ni][d] * msg_w[(D + d) * D + o];
        if (LAST) acc += nf[n * D + o];
        out_new[n * D + o] = acc;
    }
}

extern "C" void kernel_launch(void* const* d_in, const int* in_sizes, int n_in,
                              void* d_out, int out_size, void* d_ws, size_t ws_size,
                              hipStream_t stream) {
    const float* n_feat = (const float*)d_in[0];
    const float* e_feat = (const float*)d_in[1];
    const int* src = (const int*)d_in[2];
    const int* dst = (const int*)d_in[3];
    const float* lin0_w = (const float*)d_in[4];
    const float* lin0_b = (const float*)d_in[5];
    const float* msg_w = (const float*)d_in[6];
    const float* msg_b = (const float*)d_in[7];
    const float* e1_w = (const float*)d_in[8];
    const float* e1_b = (const float*)d_in[9];
    const float* e2_w = (const float*)d_in[10];
    const float* e2_b = (const float*)d_in[11];
    const float* res_w = (const float*)d_in[12];
    const float* conv_b = (const float*)d_in[13];
    float* outF = (float*)d_out;

    char* p = (char*)d_ws;
    bf16* rF = (bf16*)p;      p += (size_t)NE * DH * 2;   // 25.6 MB
    bf16* BtF = (bf16*)p;     p += (size_t)DD * DH * 2;   // 0.41 MB
    float* biasP = (float*)p; p += (size_t)DD * 4;        // 6.4 KB
    float* outA = (float*)p;  p += (size_t)NN * D * 4;    // 8 MB
    float* outB = (float*)p;  p += (size_t)NN * D * 4;    // 8 MB
    float* agg = (float*)p;   p += (size_t)NN * D * 4;    // 8 MB

    k_edge1<<<(NE * 16) / 256, 256, 0, stream>>>(e_feat, e1_w, e1_b, rF);
    k_cvtB<<<(100 * 4 * 64) / 256, 256, 0, stream>>>(e2_w, BtF);
    k_cvtBias<<<(DD + 255) / 256, 256, 0, stream>>>(e2_b, biasP);
    k_lin0<<<(NN * D + 255) / 256, 256, 0, stream>>>(n_feat, lin0_w, lin0_b, outA);
    k_zero<<<(NN * D + 255) / 256, 256, 0, stream>>>(agg, NN * D);  // once; k_node re-zeroes

    float* cur = outA;
    float* nxt = outB;
    for (int s = 0; s < 6; ++s) {
        k_msgF9<<<(NEG + 3) / 4, 256, 0, stream>>>(cur, BtF, biasP, rF, src, dst, agg);
        if (s == 5) {
            k_node<1><<<(NN + 5) / 6, 256, 0, stream>>>(cur, agg, res_w, conv_b,
                                                        msg_w, msg_b, n_feat, outF);
        } else {
            k_node<0><<<(NN + 5) / 6, 256, 0, stream>>>(cur, agg, res_w, conv_b,
                                                        msg_w, msg_b, n_feat, nxt);
            float* t = cur; cur = nxt; nxt = t;
        }
    }
}

// Round 23
// 731.319 us; speedup vs baseline: 1.0322x; 1.0322x over previous
//
#include <hip/hip_runtime.h>
#include <hip/hip_bf16.h>

#define NN 50000
#define NE 100000
#define D 40
#define DE 10
#define DH 128
#define DD 1600   // D*D
#define NEG 6250  // NE/16 edge-groups

typedef __bf16 bf16;
typedef bf16 bf16x8 __attribute__((ext_vector_type(8)));
typedef float f32x4 __attribute__((ext_vector_type(4)));

// Fragment-major layouts (one 16-B chunk per lane, contiguous per wave-load):
//   rF  idx = ((eg*4 + s)*64 + lane)*8 + j  holds r[e=eg*16+(lane&15)][k=(lane>>4)*8+s*32+j]
//   BtF idx = ((nt*4 + s)*64 + lane)*8 + j  holds e2_w[k][d*40+o], j'=nt*16+(lane&15), o=j'/40, d=j'%40

__global__ __launch_bounds__(256) void k_zero(float* __restrict__ p, int n) {
    int t = blockIdx.x * 256 + threadIdx.x;
    if (t < n) p[t] = 0.f;
}

// r (fragment-major) = relu(e_feat @ e1_w + e1_b)
__global__ __launch_bounds__(256) void k_edge1(const float* __restrict__ ef,
                                               const float* __restrict__ w,
                                               const float* __restrict__ b,
                                               bf16* __restrict__ rF) {
    int t = blockIdx.x * 256 + threadIdx.x;  // NE*16 threads exact
    int lane = t & 63;
    int e = (t >> 8) * 16 + (lane & 15);
    int kbase = (lane >> 4) * 8 + ((t >> 6) & 3) * 32;
    float efr[DE];
#pragma unroll
    for (int d = 0; d < DE; ++d) efr[d] = ef[e * DE + d];
    bf16x8 ov;
#pragma unroll
    for (int j = 0; j < 8; ++j) {
        int h = kbase + j;
        float acc = b[h];
#pragma unroll
        for (int d = 0; d < DE; ++d) acc += efr[d] * w[d * DH + h];
        ov[j] = (bf16)fmaxf(acc, 0.f);
    }
    *(bf16x8*)(rF + (size_t)t * 8) = ov;
}

// BtF fragment-major from e2_w (one-time, tiny)
__global__ __launch_bounds__(256) void k_cvtB(const float* __restrict__ w,
                                              bf16* __restrict__ btf) {
    int t = blockIdx.x * 256 + threadIdx.x;  // 100*4*64 = 25600 threads exact
    int lane = t & 63;
    int jp = (t >> 8) * 16 + (lane & 15);
    int kbase = (lane >> 4) * 8 + ((t >> 6) & 3) * 32;
    int o = jp / D, d = jp % D;
    bf16x8 ov;
#pragma unroll
    for (int j = 0; j < 8; ++j) ov[j] = (bf16)w[(kbase + j) * DD + d * D + o];
    *(bf16x8*)(btf + (size_t)t * 8) = ov;
}

// biasP[j'] = e2_b[d*40+o]
__global__ __launch_bounds__(256) void k_cvtBias(const float* __restrict__ b,
                                                 float* __restrict__ bp) {
    int t = blockIdx.x * 256 + threadIdx.x;
    if (t >= DD) return;
    int o = t / D, d = t % D;
    bp[t] = b[d * D + o];
}

// out0 = relu(n_feat @ lin0_w + lin0_b)
__global__ __launch_bounds__(256) void k_lin0(const float* __restrict__ nf,
                                              const float* __restrict__ w,
                                              const float* __restrict__ b,
                                              float* __restrict__ out) {
    int t = blockIdx.x * 256 + threadIdx.x;
    if (t >= NN * D) return;
    int o = t % D, n = t / D;
    float acc = b[o];
    const float* x = nf + n * D;
#pragma unroll
    for (int d = 0; d < D; ++d) acc += x[d] * w[d * D + o];
    out[t] = fmaxf(acc, 0.f);
}

// v7 compute core as a device function; LB variants wrap it (within-run A/B
// on the __launch_bounds__ waves-per-EU hint, which is the occupancy-limiter
// suspect: all v7-v9 variants measure ~2 waves/SIMD despite VGPR<=88).
__device__ __forceinline__ void msg_core(const float* __restrict__ x,
                                         const bf16* __restrict__ btf,
                                         const float* __restrict__ biasp,
                                         const bf16* __restrict__ rF,
                                         const int* __restrict__ src,
                                         const int* __restrict__ dst,
                                         float* __restrict__ agg,
                                         float (*mb)[16][41], int* dd_s) {
    int tid = threadIdx.x, wave = tid >> 6, lane = tid & 63;
    int r15 = lane & 15, kg = lane >> 4;
    int eg0 = blockIdx.x * 2, eg1 = eg0 + 1;  // always valid (grid exact)

    if (tid < 32) dd_s[tid] = dst[eg0 * 16 + tid];

    bf16x8 b0[4], b1[4];
#pragma unroll
    for (int s = 0; s < 4; ++s) {
        b0[s] = *(const bf16x8*)(rF + (size_t)((eg0 * 4 + s) * 64 + lane) * 8);
        b1[s] = *(const bf16x8*)(rF + (size_t)((eg1 * 4 + s) * 64 + lane) * 8);
    }
    int sv0 = src[eg0 * 16 + r15];
    int sv1 = src[eg1 * 16 + r15];
    f32x4 xq0[5], xq1[5];
#pragma unroll
    for (int i = 0; i < 5; ++i) {
        int v = 16 * i + 4 * kg;
        int d0 = v >= 40 ? v - 40 : v;  // static per (i,kg)
        xq0[i] = *(const f32x4*)(x + (size_t)sv0 * D + d0);
        xq1[i] = *(const f32x4*)(x + (size_t)sv1 * D + d0);
    }
    int m0 = wave * 5;
    int rot = blockIdx.x % 5;
    for (int j = 0; j < 5; ++j) {
        int jr = j + rot;
        int m = m0 + (jr >= 5 ? jr - 5 : jr);
        float pe0 = 0.f, po0 = 0.f, pe1 = 0.f, po1 = 0.f;
#pragma unroll
        for (int i = 0; i < 5; ++i) {
            int nt = m * 5 + i;
            bf16x8 af[4];
#pragma unroll
            for (int s = 0; s < 4; ++s)
                af[s] = *(const bf16x8*)(btf + (size_t)((nt * 4 + s) * 64 + lane) * 8);
            f32x4 bias = *(const f32x4*)(biasp + nt * 16 + kg * 4);
            f32x4 a0 = {0.f, 0.f, 0.f, 0.f}, a1 = {0.f, 0.f, 0.f, 0.f};
#pragma unroll
            for (int s = 0; s < 4; ++s) {
                a0 = __builtin_amdgcn_mfma_f32_16x16x32_bf16(af[s], b0[s], a0, 0, 0, 0);
                a1 = __builtin_amdgcn_mfma_f32_16x16x32_bf16(af[s], b1[s], a1, 0, 0, 0);
            }
            f32x4 xv0 = xq0[i], xv1 = xq1[i];
            float p0 = (a0[0] + bias[0]) * xv0[0] + (a0[1] + bias[1]) * xv0[1] +
                       (a0[2] + bias[2]) * xv0[2] + (a0[3] + bias[3]) * xv0[3];
            float p1 = (a1[0] + bias[0]) * xv1[0] + (a1[1] + bias[1]) * xv1[1] +
                       (a1[2] + bias[2]) * xv1[2] + (a1[3] + bias[3]) * xv1[3];
            if (i <= 1) { pe0 += p0; pe1 += p1; }       // 16i+4kg < 40 always
            else if (i >= 3) { po0 += p0; po1 += p1; }  // >= 40 always
            else {                                       // i==2: kg>=2 -> hi
                bool hi = kg >= 2;
                pe0 += hi ? 0.f : p0; po0 += hi ? p0 : 0.f;
                pe1 += hi ? 0.f : p1; po1 += hi ? p1 : 0.f;
            }
        }
        pe0 += __shfl_xor(pe0, 16, 64); pe0 += __shfl_xor(pe0, 32, 64);
        po0 += __shfl_xor(po0, 16, 64); po0 += __shfl_xor(po0, 32, 64);
        pe1 += __shfl_xor(pe1, 16, 64); pe1 += __shfl_xor(pe1, 32, 64);
        po1 += __shfl_xor(po1, 16, 64); po1 += __shfl_xor(po1, 32, 64);
        if (lane < 16) {  // plain stores: unique (group, edge, o) per lane
            mb[0][r15][2 * m] = pe0;
            mb[0][r15][2 * m + 1] = po0;
            mb[1][r15][2 * m] = pe1;
            mb[1][r15][2 * m + 1] = po1;
        }
    }
    __syncthreads();
    // coalesced flush: consecutive tid -> consecutive o of same edge row
#pragma unroll
    for (int idx = tid; idx < 2 * 16 * D; idx += 256) {
        int gl = idx / (16 * D), rem = idx % (16 * D);
        int e_l = rem / D, o = rem % D;
        atomicAdd(&agg[(size_t)dd_s[gl * 16 + e_l] * D + o], mb[gl][e_l][o]);
    }
}

// Variant A: the proven (256,2) hint (82 us/step, occ 26%)
__global__ __launch_bounds__(256, 2) void k_msgA(const float* __restrict__ x,
                                                 const bf16* __restrict__ btf,
                                                 const float* __restrict__ biasp,
                                                 const bf16* __restrict__ rF,
                                                 const int* __restrict__ src,
                                                 const int* __restrict__ dst,
                                                 float* __restrict__ agg) {
    __shared__ float mb[2][16][41];
    __shared__ int dd_s[32];
    msg_core(x, btf, biasp, rF, src, dst, agg, mb, dd_s);
}

// Variant B: no waves-per-EU hint (test: does the hint cap residency?)
__global__ __launch_bounds__(256) void k_msgB(const float* __restrict__ x,
                                              const bf16* __restrict__ btf,
                                              const float* __restrict__ biasp,
                                              const bf16* __restrict__ rF,
                                              const int* __restrict__ src,
                                              const int* __restrict__ dst,
                                              float* __restrict__ agg) {
    __shared__ float mb[2][16][41];
    __shared__ int dd_s[32];
    msg_core(x, btf, biasp, rF, src, dst, agg, mb, dd_s);
}

// node update: m = relu(agg + out@res_w + conv_b); out' = [m,out]@msg_w + msg_b
// (+ n_feat if LAST). Non-LAST also re-zeroes agg for the next step.
template <int LAST>
__global__ __launch_bounds__(256) void k_node(const float* __restrict__ out,
                                              float* __restrict__ agg,
                                              const float* __restrict__ res_w,
                                              const float* __restrict__ conv_b,
                                              const float* __restrict__ msg_w,
                                              const float* __restrict__ msg_b,
                                              const float* __restrict__ nf,
                                              float* __restrict__ out_new) {
    __shared__ float xs[6][D], ms[6][D];
    int ni = threadIdx.x / D, o = threadIdx.x % D;
    int n = blockIdx.x * 6 + ni;
    bool ok = (ni < 6) && (n < NN);
    if (ok) xs[ni][o] = out[n * D + o];
    __syncthreads();
    if (ok) {
        float t = conv_b[o] + agg[n * D + o];
        if (!LAST) agg[n * D + o] = 0.f;  // re-zero for next step's atomics
#pragma unroll
        for (int d = 0; d < D; ++d) t += xs[ni][d] * res_w[d * D + o];
        ms[ni][o] = fmaxf(t, 0.f);
    }
    __syncthreads();
    if (ok) {
        float acc = msg_b[o];
#pragma unroll
        for (int d = 0; d < D; ++d)
            acc += ms[ni][d] * msg_w[d * D + o] + xs[ni][d] * msg_w[(D + d) * D + o];
        if (LAST) acc += nf[n * D + o];
        out_new[n * D + o] = acc;
    }
}

extern "C" void kernel_launch(void* const* d_in, const int* in_sizes, int n_in,
                              void* d_out, int out_size, void* d_ws, size_t ws_size,
                              hipStream_t stream) {
    const float* n_feat = (const float*)d_in[0];
    const float* e_feat = (const float*)d_in[1];
    const int* src = (const int*)d_in[2];
    const int* dst = (const int*)d_in[3];
    const float* lin0_w = (const float*)d_in[4];
    const float* lin0_b = (const float*)d_in[5];
    const float* msg_w = (const float*)d_in[6];
    const float* msg_b = (const float*)d_in[7];
    const float* e1_w = (const float*)d_in[8];
    const float* e1_b = (const float*)d_in[9];
    const float* e2_w = (const float*)d_in[10];
    const float* e2_b = (const float*)d_in[11];
    const float* res_w = (const float*)d_in[12];
    const float* conv_b = (const float*)d_in[13];
    float* outF = (float*)d_out;

    char* p = (char*)d_ws;
    bf16* rF = (bf16*)p;      p += (size_t)NE * DH * 2;   // 25.6 MB
    bf16* BtF = (bf16*)p;     p += (size_t)DD * DH * 2;   // 0.41 MB
    float* biasP = (float*)p; p += (size_t)DD * 4;        // 6.4 KB
    float* outA = (float*)p;  p += (size_t)NN * D * 4;    // 8 MB
    float* outB = (float*)p;  p += (size_t)NN * D * 4;    // 8 MB
    float* agg = (float*)p;   p += (size_t)NN * D * 4;    // 8 MB

    k_edge1<<<(NE * 16) / 256, 256, 0, stream>>>(e_feat, e1_w, e1_b, rF);
    k_cvtB<<<(100 * 4 * 64) / 256, 256, 0, stream>>>(e2_w, BtF);
    k_cvtBias<<<(DD + 255) / 256, 256, 0, stream>>>(e2_b, biasP);
    k_lin0<<<(NN * D + 255) / 256, 256, 0, stream>>>(n_feat, lin0_w, lin0_b, outA);
    k_zero<<<(NN * D + 255) / 256, 256, 0, stream>>>(agg, NN * D);  // once; k_node re-zeroes

    float* cur = outA;
    float* nxt = outB;
    for (int s = 0; s < 6; ++s) {
        if (s & 1)
            k_msgB<<<NEG / 2, 256, 0, stream>>>(cur, BtF, biasP, rF, src, dst, agg);
        else
            k_msgA<<<NEG / 2, 256, 0, stream>>>(cur, BtF, biasP, rF, src, dst, agg);
        if (s == 5) {
            k_node<1><<<(NN + 5) / 6, 256, 0, stream>>>(cur, agg, res_w, conv_b,
                                                        msg_w, msg_b, n_feat, outF);
        } else {
            k_node<0><<<(NN + 5) / 6, 256, 0, stream>>>(cur, agg, res_w, conv_b,
                                                        msg_w, msg_b, n_feat, nxt);
            float* t = cur; cur = nxt; nxt = t;
        }
    }
}

// Round 24
// 698.792 us; speedup vs baseline: 1.0802x; 1.0465x over previous
//
#include <hip/hip_runtime.h>
#include <hip/hip_bf16.h>

#define NN 50000
#define NE 100000
#define D 40
#define DE 10
#define DH 128
#define DD 1600   // D*D
#define NEG 6250  // NE/16 edge-groups

typedef __bf16 bf16;
typedef bf16 bf16x8 __attribute__((ext_vector_type(8)));
typedef float f32x4 __attribute__((ext_vector_type(4)));

// Fragment-major layouts (one 16-B chunk per lane, contiguous per wave-load):
//   rF  idx = ((eg*4 + s)*64 + lane)*8 + j  holds r[e=eg*16+(lane&15)][k=(lane>>4)*8+s*32+j]
//   BtF idx = ((nt*4 + s)*64 + lane)*8 + j  holds e2_w[k][d*40+o], j'=nt*16+(lane&15), o=j'/40, d=j'%40

__global__ __launch_bounds__(256) void k_zero(float* __restrict__ p, int n) {
    int t = blockIdx.x * 256 + threadIdx.x;
    if (t < n) p[t] = 0.f;
}

// r (fragment-major) = relu(e_feat @ e1_w + e1_b)
__global__ __launch_bounds__(256) void k_edge1(const float* __restrict__ ef,
                                               const float* __restrict__ w,
                                               const float* __restrict__ b,
                                               bf16* __restrict__ rF) {
    int t = blockIdx.x * 256 + threadIdx.x;  // NE*16 threads exact
    int lane = t & 63;
    int e = (t >> 8) * 16 + (lane & 15);
    int kbase = (lane >> 4) * 8 + ((t >> 6) & 3) * 32;
    float efr[DE];
#pragma unroll
    for (int d = 0; d < DE; ++d) efr[d] = ef[e * DE + d];
    bf16x8 ov;
#pragma unroll
    for (int j = 0; j < 8; ++j) {
        int h = kbase + j;
        float acc = b[h];
#pragma unroll
        for (int d = 0; d < DE; ++d) acc += efr[d] * w[d * DH + h];
        ov[j] = (bf16)fmaxf(acc, 0.f);
    }
    *(bf16x8*)(rF + (size_t)t * 8) = ov;
}

// BtF fragment-major from e2_w (one-time, tiny)
__global__ __launch_bounds__(256) void k_cvtB(const float* __restrict__ w,
                                              bf16* __restrict__ btf) {
    int t = blockIdx.x * 256 + threadIdx.x;  // 100*4*64 = 25600 threads exact
    int lane = t & 63;
    int jp = (t >> 8) * 16 + (lane & 15);
    int kbase = (lane >> 4) * 8 + ((t >> 6) & 3) * 32;
    int o = jp / D, d = jp % D;
    bf16x8 ov;
#pragma unroll
    for (int j = 0; j < 8; ++j) ov[j] = (bf16)w[(kbase + j) * DD + d * D + o];
    *(bf16x8*)(btf + (size_t)t * 8) = ov;
}

// biasP[j'] = e2_b[d*40+o]
__global__ __launch_bounds__(256) void k_cvtBias(const float* __restrict__ b,
                                                 float* __restrict__ bp) {
    int t = blockIdx.x * 256 + threadIdx.x;
    if (t >= DD) return;
    int o = t / D, d = t % D;
    bp[t] = b[d * D + o];
}

// out0 = relu(n_feat @ lin0_w + lin0_b)
__global__ __launch_bounds__(256) void k_lin0(const float* __restrict__ nf,
                                              const float* __restrict__ w,
                                              const float* __restrict__ b,
                                              float* __restrict__ out) {
    int t = blockIdx.x * 256 + threadIdx.x;
    if (t >= NN * D) return;
    int o = t % D, n = t / D;
    float acc = b[o];
    const float* x = nf + n * D;
#pragma unroll
    for (int d = 0; d < D; ++d) acc += x[d] * w[d * D + o];
    out[t] = fmaxf(acc, 0.f);
}

// Fused message step v10 = v7 (4-way nt-split, rotated m-order, proven 82us)
// + s_setprio(1) around the MFMA cluster (T5: helps independent-wave kernels
// where waves sit at decorrelated phases; zero correctness risk).
__global__ __launch_bounds__(256, 2) void k_msgF10(const float* __restrict__ x,
                                                   const bf16* __restrict__ btf,
                                                   const float* __restrict__ biasp,
                                                   const bf16* __restrict__ rF,
                                                   const int* __restrict__ src,
                                                   const int* __restrict__ dst,
                                                   float* __restrict__ agg) {
    __shared__ float mb[2][16][41];  // 5.25 KB
    __shared__ int dd_s[32];
    int tid = threadIdx.x, wave = tid >> 6, lane = tid & 63;
    int r15 = lane & 15, kg = lane >> 4;
    int eg0 = blockIdx.x * 2, eg1 = eg0 + 1;  // always valid (grid exact)

    if (tid < 32) dd_s[tid] = dst[eg0 * 16 + tid];

    bf16x8 b0[4], b1[4];
#pragma unroll
    for (int s = 0; s < 4; ++s) {
        b0[s] = *(const bf16x8*)(rF + (size_t)((eg0 * 4 + s) * 64 + lane) * 8);
        b1[s] = *(const bf16x8*)(rF + (size_t)((eg1 * 4 + s) * 64 + lane) * 8);
    }
    int sv0 = src[eg0 * 16 + r15];
    int sv1 = src[eg1 * 16 + r15];
    f32x4 xq0[5], xq1[5];
#pragma unroll
    for (int i = 0; i < 5; ++i) {
        int v = 16 * i + 4 * kg;
        int d0 = v >= 40 ? v - 40 : v;  // static per (i,kg)
        xq0[i] = *(const f32x4*)(x + (size_t)sv0 * D + d0);
        xq1[i] = *(const f32x4*)(x + (size_t)sv1 * D + d0);
    }
    int m0 = wave * 5;
    int rot = blockIdx.x % 5;
    for (int j = 0; j < 5; ++j) {
        int jr = j + rot;
        int m = m0 + (jr >= 5 ? jr - 5 : jr);
        float pe0 = 0.f, po0 = 0.f, pe1 = 0.f, po1 = 0.f;
#pragma unroll
        for (int i = 0; i < 5; ++i) {
            int nt = m * 5 + i;
            bf16x8 af[4];
#pragma unroll
            for (int s = 0; s < 4; ++s)
                af[s] = *(const bf16x8*)(btf + (size_t)((nt * 4 + s) * 64 + lane) * 8);
            f32x4 bias = *(const f32x4*)(biasp + nt * 16 + kg * 4);
            f32x4 a0 = {0.f, 0.f, 0.f, 0.f}, a1 = {0.f, 0.f, 0.f, 0.f};
            __builtin_amdgcn_s_setprio(1);
#pragma unroll
            for (int s = 0; s < 4; ++s) {
                a0 = __builtin_amdgcn_mfma_f32_16x16x32_bf16(af[s], b0[s], a0, 0, 0, 0);
                a1 = __builtin_amdgcn_mfma_f32_16x16x32_bf16(af[s], b1[s], a1, 0, 0, 0);
            }
            __builtin_amdgcn_s_setprio(0);
            f32x4 xv0 = xq0[i], xv1 = xq1[i];
            float p0 = (a0[0] + bias[0]) * xv0[0] + (a0[1] + bias[1]) * xv0[1] +
                       (a0[2] + bias[2]) * xv0[2] + (a0[3] + bias[3]) * xv0[3];
            float p1 = (a1[0] + bias[0]) * xv1[0] + (a1[1] + bias[1]) * xv1[1] +
                       (a1[2] + bias[2]) * xv1[2] + (a1[3] + bias[3]) * xv1[3];
            if (i <= 1) { pe0 += p0; pe1 += p1; }       // 16i+4kg < 40 always
            else if (i >= 3) { po0 += p0; po1 += p1; }  // >= 40 always
            else {                                       // i==2: kg>=2 -> hi
                bool hi = kg >= 2;
                pe0 += hi ? 0.f : p0; po0 += hi ? p0 : 0.f;
                pe1 += hi ? 0.f : p1; po1 += hi ? p1 : 0.f;
            }
        }
        pe0 += __shfl_xor(pe0, 16, 64); pe0 += __shfl_xor(pe0, 32, 64);
        po0 += __shfl_xor(po0, 16, 64); po0 += __shfl_xor(po0, 32, 64);
        pe1 += __shfl_xor(pe1, 16, 64); pe1 += __shfl_xor(pe1, 32, 64);
        po1 += __shfl_xor(po1, 16, 64); po1 += __shfl_xor(po1, 32, 64);
        if (lane < 16) {  // plain stores: unique (group, edge, o) per lane
            mb[0][r15][2 * m] = pe0;
            mb[0][r15][2 * m + 1] = po0;
            mb[1][r15][2 * m] = pe1;
            mb[1][r15][2 * m + 1] = po1;
        }
    }
    __syncthreads();
    // coalesced flush: consecutive tid -> consecutive o of same edge row
#pragma unroll
    for (int idx = tid; idx < 2 * 16 * D; idx += 256) {
        int gl = idx / (16 * D), rem = idx % (16 * D);
        int e_l = rem / D, o = rem % D;
        atomicAdd(&agg[(size_t)dd_s[gl * 16 + e_l] * D + o], mb[gl][e_l][o]);
    }
}

// node update: m = relu(agg + out@res_w + conv_b); out' = [m,out]@msg_w + msg_b
// (+ n_feat if LAST). Non-LAST also re-zeroes agg for the next step.
template <int LAST>
__global__ __launch_bounds__(256) void k_node(const float* __restrict__ out,
                                              float* __restrict__ agg,
                                              const float* __restrict__ res_w,
                                              const float* __restrict__ conv_b,
                                              const float* __restrict__ msg_w,
                                              const float* __restrict__ msg_b,
                                              const float* __restrict__ nf,
                                              float* __restrict__ out_new) {
    __shared__ float xs[6][D], ms[6][D];
    int ni = threadIdx.x / D, o = threadIdx.x % D;
    int n = blockIdx.x * 6 + ni;
    bool ok = (ni < 6) && (n < NN);
    if (ok) xs[ni][o] = out[n * D + o];
    __syncthreads();
    if (ok) {
        float t = conv_b[o] + agg[n * D + o];
        if (!LAST) agg[n * D + o] = 0.f;  // re-zero for next step's atomics
#pragma unroll
        for (int d = 0; d < D; ++d) t += xs[ni][d] * res_w[d * D + o];
        ms[ni][o] = fmaxf(t, 0.f);
    }
    __syncthreads();
    if (ok) {
        float acc = msg_b[o];
#pragma unroll
        for (int d = 0; d < D; ++d)
            acc += ms[ni][d] * msg_w[d * D + o] + xs[ni][d] * msg_w[(D + d) * D + o];
        if (LAST) acc += nf[n * D + o];
        out_new[n * D + o] = acc;
    }
}

extern "C" void kernel_launch(void* const* d_in, const int* in_sizes, int n_in,
                              void* d_out, int out_size, void* d_ws, size_t ws_size,
                              hipStream_t stream) {
    const float* n_feat = (const float*)d_in[0];
    const float* e_feat = (const float*)d_in[1];
    const int* src = (const int*)d_in[2];
    const int* dst = (const int*)d_in[3];
    const float* lin0_w = (const float*)d_in[4];
    const float* lin0_b = (const float*)d_in[5];
    const float* msg_w = (const float*)d_in[6];
    const float* msg_b = (const float*)d_in[7];
    const float* e1_w = (const float*)d_in[8];
    const float* e1_b = (const float*)d_in[9];
    const float* e2_w = (const float*)d_in[10];
    const float* e2_b = (const float*)d_in[11];
    const float* res_w = (const float*)d_in[12];
    const float* conv_b = (const float*)d_in[13];
    float* outF = (float*)d_out;

    char* p = (char*)d_ws;
    bf16* rF = (bf16*)p;      p += (size_t)NE * DH * 2;   // 25.6 MB
    bf16* BtF = (bf16*)p;     p += (size_t)DD * DH * 2;   // 0.41 MB
    float* biasP = (float*)p; p += (size_t)DD * 4;        // 6.4 KB
    float* outA = (float*)p;  p += (size_t)NN * D * 4;    // 8 MB
    float* outB = (float*)p;  p += (size_t)NN * D * 4;    // 8 MB
    float* agg = (float*)p;   p += (size_t)NN * D * 4;    // 8 MB

    k_edge1<<<(NE * 16) / 256, 256, 0, stream>>>(e_feat, e1_w, e1_b, rF);
    k_cvtB<<<(100 * 4 * 64) / 256, 256, 0, stream>>>(e2_w, BtF);
    k_cvtBias<<<(DD + 255) / 256, 256, 0, stream>>>(e2_b, biasP);
    k_lin0<<<(NN * D + 255) / 256, 256, 0, stream>>>(n_feat, lin0_w, lin0_b, outA);
    k_zero<<<(NN * D + 255) / 256, 256, 0, stream>>>(agg, NN * D);  // once; k_node re-zeroes

    float* cur = outA;
    float* nxt = outB;
    for (int s = 0; s < 6; ++s) {
        k_msgF10<<<NEG / 2, 256, 0, stream>>>(cur, BtF, biasP, rF, src, dst, agg);
        if (s == 5) {
            k_node<1><<<(NN + 5) / 6, 256, 0, stream>>>(cur, agg, res_w, conv_b,
                                                        msg_w, msg_b, n_feat, outF);
        } else {
            k_node<0><<<(NN + 5) / 6, 256, 0, stream>>>(cur, agg, res_w, conv_b,
                                                        msg_w, msg_b, n_feat, nxt);
            float* t = cur; cur = nxt; nxt = t;
        }
    }
}